// Round 8
// baseline (546.405 us; speedup 1.0000x reference)
//
#include <hip/hip_runtime.h>

#define BB 64
#define TT 1024
#define CC 256

typedef short v8s __attribute__((ext_vector_type(8)));
typedef int   v4i __attribute__((ext_vector_type(4)));
typedef float v4f __attribute__((ext_vector_type(4)));

#define REP8(X) X(0) X(1) X(2) X(3) X(4) X(5) X(6) X(7)

// fp32 -> bf16 round-to-nearest-even (finite inputs)
static __device__ __forceinline__ short f2bf(float f) {
  unsigned u = __float_as_uint(f);
  return (short)((u + 0x7FFFu + ((u >> 16) & 1u)) >> 16);
}

// LDS-only barrier: lgkmcnt(0) + s_barrier, no vmcnt drain.
static __device__ __forceinline__ void fast_barrier() {
  asm volatile("s_waitcnt lgkmcnt(0)\n\ts_barrier" ::: "memory");
}

// 768 thr = 12 waves per block, one block per batch chain, 1 barrier/step.
// (R7 structure — best measured at 445.8us/dispatch. R8 delta: the T5
//  setprio(1) window now covers the ENTIRE MFMA-wave step body — the 8
//  A-chunk ds_reads + sigma/rcp at the head and the r-sum/v/f2bf/ds_write
//  tail were previously outside it, letting helper exp/log/store streams
//  steal issue slots during the two latency-critical flanks.)
// Step-time budget (R7 post-mortem): 1044 cyc/step = ~620 MFMA-pipe
//   (32 MFMA/SIMD x ~19.4 cyc — hard floor at bf16; 16x M-row redundancy
//   unfixable: W is per-batch so no second vector exists to share B) +
//   ~250 handoff (a0 latency + drain + tail + barrier) + ~170-250 slop.
// Waves 0-7 : MFMA-only. Wave w owns cols {w*32+nl, +16}; W = exp(trans)
//             register-resident as 16 named bf16 B-fragments.
// Waves 8-11: helpers, lane j = tid-512. Prefetch e (distance 2, unroll-2
//             alternating regs), stage E_{t+1}=exp(e_{t+1}) one step ahead
//             (s_E dbuf), deferred alpha_{t-1} = log(P bf16) + C, store,
//             C += log(sigma), s_last. sigma read as bf16 from s_pbf[RB][0]
//             — same bits as MFMA waves' readfirstlane value, so the
//             rescale cancellation in alpha stays exact.
// Recurrence (exp domain): P_t = E_t (.) (W^T P_{t-1}) / sigma_t,
//   sigma_t = P_{t-1}[0] (bf16), C_t = C_{t-1} + log sigma_t,
//   alpha_t = log P_t + C_t.  Range: P in [e^-34, e^25] worst case — safe.
__global__ __launch_bounds__(768, 3)
void crf_fwd(const float* __restrict__ emis,      // [B,T,C]
             const float* __restrict__ trans,     // [B,C,C]
             const int* __restrict__ seq_lens,    // [B]
             float* __restrict__ out_alpha,       // [B,T,C]
             float* __restrict__ out_logz)        // [B]
{
  const int b = blockIdx.x;
  const int tid = threadIdx.x;
  const int lane = tid & 63;
  const int wv = tid >> 6;        // 0..7 MFMA, 8..11 helper
  const int quad = lane >> 4;
  const int nl = lane & 15;
  const int k0q = quad * 8;
  const int col0 = (wv & 7) * 32 + nl;
  const int col1 = col0 + 16;
  const int j = tid - 512;        // helper column (negative for MFMA waves)

  __shared__ unsigned short __align__(16) s_pbf[2][CC];  // P (bf16), dbuf
  __shared__ float s_E[2][CC];                           // staged exp(e_t)
  __shared__ float __align__(16) s_last[CC];             // alpha at L-1

  const float* eb = emis + (size_t)b * TT * CC;
  float* ab = out_alpha + (size_t)b * TT * CC;
  const int L = seq_lens[b];

  // ---- B fragments (declared for all; initialized/used only by wv<8) ----
#define DECLB(q) v8s B0_##q, B1_##q;
  REP8(DECLB)

  float C = 0.f, LA = 0.f, LB = 0.f;   // helper state

  if (wv < 8) {
    const float* tb = trans + (size_t)b * CC * CC;
    const int n0 = col0;
#define INITB(q) { \
    const float* pp = tb + (size_t)(q * 32 + k0q) * CC + n0; \
    B0_##q = (v8s){ f2bf(__expf(pp[0*CC])), f2bf(__expf(pp[1*CC])), \
                    f2bf(__expf(pp[2*CC])), f2bf(__expf(pp[3*CC])), \
                    f2bf(__expf(pp[4*CC])), f2bf(__expf(pp[5*CC])), \
                    f2bf(__expf(pp[6*CC])), f2bf(__expf(pp[7*CC])) }; \
    const float* qq = pp + 16; \
    B1_##q = (v8s){ f2bf(__expf(qq[0*CC])), f2bf(__expf(qq[1*CC])), \
                    f2bf(__expf(qq[2*CC])), f2bf(__expf(qq[3*CC])), \
                    f2bf(__expf(qq[4*CC])), f2bf(__expf(qq[5*CC])), \
                    f2bf(__expf(qq[6*CC])), f2bf(__expf(qq[7*CC])) }; }
    REP8(INITB)
  } else {
    // ---- helper prologue: t = 0 state ----
    float e0j = eb[j];
    float a00 = eb[0];
    ab[j] = e0j;                                   // alpha_0 exact
    C = a00;                                       // C_0
    s_pbf[0][j] = (unsigned short)f2bf(__expf(e0j - a00));
    // note: j==0 gives f2bf(exp(0)) = 1.0 exactly -> sigma_1 = 1.0
    if (L == 1) s_last[j] = e0j;
    s_E[1][j] = __expf(eb[CC + j]);                // E_1 for step t=1
    LB = eb[2 * CC + j];                           // e[2] in flight
  }
  const v4f z4 = {0.f, 0.f, 0.f, 0.f};
  __syncthreads();

  // ---- step macros ----
#define MSTEP(T, RB, WB) { \
    const unsigned short* pbR = s_pbf[RB]; \
    __builtin_amdgcn_s_setprio(1);   /* T5: full-body window (R8) */ \
    /* all 8 A-chunk reads issued back-to-back, before any lgkm use */ \
    v8s a0 = *(const v8s*)(const void*)(pbR + 0 * 32 + k0q); \
    v8s a1 = *(const v8s*)(const void*)(pbR + 1 * 32 + k0q); \
    v8s a2 = *(const v8s*)(const void*)(pbR + 2 * 32 + k0q); \
    v8s a3 = *(const v8s*)(const void*)(pbR + 3 * 32 + k0q); \
    v8s a4 = *(const v8s*)(const void*)(pbR + 4 * 32 + k0q); \
    v8s a5 = *(const v8s*)(const void*)(pbR + 5 * 32 + k0q); \
    v8s a6 = *(const v8s*)(const void*)(pbR + 6 * 32 + k0q); \
    v8s a7 = *(const v8s*)(const void*)(pbR + 7 * 32 + k0q); \
    float E0 = s_E[WB][col0]; \
    float E1 = s_E[WB][col1]; \
    unsigned pf = (unsigned)__builtin_amdgcn_readfirstlane(((v4i)a0)[0]); \
    float sig = __uint_as_float(pf << 16);                /* P_{t-1}[0] */ \
    float inv = __builtin_amdgcn_rcpf(sig); \
    v4f c0a, c0b, c1a, c1b; \
    c0a = __builtin_amdgcn_mfma_f32_16x16x32_bf16(a0, B0_0, z4, 0, 0, 0); \
    c1a = __builtin_amdgcn_mfma_f32_16x16x32_bf16(a0, B1_0, z4, 0, 0, 0); \
    c0b = __builtin_amdgcn_mfma_f32_16x16x32_bf16(a4, B0_4, z4, 0, 0, 0); \
    c1b = __builtin_amdgcn_mfma_f32_16x16x32_bf16(a4, B1_4, z4, 0, 0, 0); \
    c0a = __builtin_amdgcn_mfma_f32_16x16x32_bf16(a1, B0_1, c0a, 0, 0, 0); \
    c1a = __builtin_amdgcn_mfma_f32_16x16x32_bf16(a1, B1_1, c1a, 0, 0, 0); \
    c0b = __builtin_amdgcn_mfma_f32_16x16x32_bf16(a5, B0_5, c0b, 0, 0, 0); \
    c1b = __builtin_amdgcn_mfma_f32_16x16x32_bf16(a5, B1_5, c1b, 0, 0, 0); \
    c0a = __builtin_amdgcn_mfma_f32_16x16x32_bf16(a2, B0_2, c0a, 0, 0, 0); \
    c1a = __builtin_amdgcn_mfma_f32_16x16x32_bf16(a2, B1_2, c1a, 0, 0, 0); \
    c0b = __builtin_amdgcn_mfma_f32_16x16x32_bf16(a6, B0_6, c0b, 0, 0, 0); \
    c1b = __builtin_amdgcn_mfma_f32_16x16x32_bf16(a6, B1_6, c1b, 0, 0, 0); \
    c0a = __builtin_amdgcn_mfma_f32_16x16x32_bf16(a3, B0_3, c0a, 0, 0, 0); \
    c1a = __builtin_amdgcn_mfma_f32_16x16x32_bf16(a3, B1_3, c1a, 0, 0, 0); \
    c0b = __builtin_amdgcn_mfma_f32_16x16x32_bf16(a7, B0_7, c0b, 0, 0, 0); \
    c1b = __builtin_amdgcn_mfma_f32_16x16x32_bf16(a7, B1_7, c1b, 0, 0, 0); \
    float Ei0 = E0 * inv;                 /* in the MFMA shadow */ \
    float Ei1 = E1 * inv; \
    float r0 = c0a[0] + c0b[0]; \
    float r1 = c1a[0] + c1b[0]; \
    float v0 = Ei0 * r0; \
    float v1 = Ei1 * r1; \
    if (quad < 2) \
      s_pbf[WB][col0 + (quad << 4)] = (unsigned short)f2bf(quad ? v1 : v0); \
    __builtin_amdgcn_s_setprio(0);   /* drop after the P write */ \
  }

  // helper: at step T stage E_{T+1} into s_E[(T+1)&1] == s_E[RB]
#define HSTEP(T, RB, WB, LDREG, USEREG) { \
    int tp2 = (T) + 2; if (tp2 > TT - 1) tp2 = TT - 1; \
    LDREG = eb[(size_t)tp2 * CC + j]; \
    unsigned short sg = s_pbf[RB][0];                     /* sigma bf16 */ \
    float sig = __uint_as_float(((unsigned)sg) << 16); \
    float P = __uint_as_float(((unsigned)s_pbf[RB][j]) << 16); \
    float a_prev = __logf(P) + C; \
    if ((T) >= 2) ab[(size_t)((T) - 1) * CC + j] = a_prev; \
    if ((T) == L) s_last[j] = a_prev; \
    C += __logf(sig); \
    if ((T) < TT - 1) s_E[RB][j] = __expf(USEREG); \
  }

  // ---- main chain: unroll-2, one fast_barrier per step ----
  for (int t = 1; t + 1 < TT; t += 2) {
    if (wv < 8) { MSTEP(t, 0, 1) } else { HSTEP(t, 0, 1, LA, LB) }
    fast_barrier();
    if (wv < 8) { MSTEP(t + 1, 1, 0) } else { HSTEP(t + 1, 1, 0, LB, LA) }
    fast_barrier();
  }
  // tail step t = TT-1 (odd): RB=0, WB=1
  if (wv < 8) { MSTEP(TT - 1, 0, 1) } else { HSTEP(TT - 1, 0, 1, LA, LB) }
  fast_barrier();

  // ---- epilogue: alpha_{TT-1} by helpers, then log_Z ----
  if (wv >= 8) {
    float P = __uint_as_float(((unsigned)s_pbf[(TT - 1) & 1][j]) << 16);
    float a_last = __logf(P) + C;                  // C == C_{TT-1}
    ab[(size_t)(TT - 1) * CC + j] = a_last;
    if (L == TT) s_last[j] = a_last;
  }
  __syncthreads();

  if (tid < 64) {
    float4 v = ((const float4*)s_last)[lane];
    float m = fmaxf(fmaxf(v.x, v.y), fmaxf(v.z, v.w));
    #pragma unroll
    for (int off = 32; off >= 1; off >>= 1)
      m = fmaxf(m, __shfl_xor(m, off, 64));
    float s = __expf(v.x - m) + __expf(v.y - m) + __expf(v.z - m) + __expf(v.w - m);
    #pragma unroll
    for (int off = 32; off >= 1; off >>= 1)
      s += __shfl_xor(s, off, 64);
    if (lane == 0) out_logz[b] = m + __logf(s);
  }
}

extern "C" void kernel_launch(void* const* d_in, const int* in_sizes, int n_in,
                              void* d_out, int out_size, void* d_ws, size_t ws_size,
                              hipStream_t stream) {
  const float* emis = (const float*)d_in[0];
  const float* trans = (const float*)d_in[1];
  const int* seq_lens = (const int*)d_in[2];
  float* out_alpha = (float*)d_out;
  float* out_logz = out_alpha + (size_t)BB * TT * CC;
  hipLaunchKernelGGL(crf_fwd, dim3(BB), dim3(768), 0, stream,
                     emis, trans, seq_lens, out_alpha, out_logz);
}

// Round 9
// 527.033 us; speedup vs baseline: 1.0368x; 1.0368x over previous
//
#include <hip/hip_runtime.h>

#define BB 64
#define TT 1024
#define CC 256

typedef short v8s __attribute__((ext_vector_type(8)));
typedef int   v4i __attribute__((ext_vector_type(4)));
typedef float v4f __attribute__((ext_vector_type(4)));

#define REP8(X) X(0) X(1) X(2) X(3) X(4) X(5) X(6) X(7)

// fp32 -> bf16 round-to-nearest-even (finite inputs)
static __device__ __forceinline__ short f2bf(float f) {
  unsigned u = __float_as_uint(f);
  return (short)((u + 0x7FFFu + ((u >> 16) & 1u)) >> 16);
}

// LDS-only barrier: lgkmcnt(0) + s_barrier, no vmcnt drain.
static __device__ __forceinline__ void fast_barrier() {
  asm volatile("s_waitcnt lgkmcnt(0)\n\ts_barrier" ::: "memory");
}

// 768 thr = 12 waves per block, one block per batch chain, 1 barrier/step.
// (R7 structure restored — best measured at 445.8us/dispatch. R8's
//  full-body setprio window REGRESSED +4%: holding prio through the
//  ds_read wait and tail starved the helper waves for the whole body,
//  serializing their ~400-cyc HSTEP stream after the MFMA stream. The
//  narrow window — prio raised only during the 16-MFMA burst, where MFMA
//  waves need no VALU issue slots — is the correct shape (T5/m191).)
// Step-time budget: ~1044 cyc/step = ~620 MFMA-pipe (32 MFMA/SIMD x
//   ~19.4 cyc — hard floor at bf16; 16x M-row redundancy is the price of
//   MFMA's free A-broadcast; VALU matvec needs ~85 broadcast ds_reads per
//   wave per step, strictly worse) + ~250 handoff (a0 ds_read latency +
//   MFMA drain + tail + barrier) + ~170 slop (incompressible per R5/R6/R8).
// Waves 0-7 : MFMA-only. Wave w owns cols {w*32+nl, +16}; W = exp(trans)
//             register-resident as 16 named bf16 B-fragments.
// Waves 8-11: helpers, lane j = tid-512. Prefetch e (distance 2, unroll-2
//             alternating regs), stage E_{t+1}=exp(e_{t+1}) one step ahead
//             (s_E dbuf), deferred alpha_{t-1} = log(P bf16) + C, store,
//             C += log(sigma), s_last. sigma read as bf16 from s_pbf[RB][0]
//             — same bits as MFMA waves' readfirstlane value, so the
//             rescale cancellation in alpha stays exact.
// Recurrence (exp domain): P_t = E_t (.) (W^T P_{t-1}) / sigma_t,
//   sigma_t = P_{t-1}[0] (bf16), C_t = C_{t-1} + log sigma_t,
//   alpha_t = log P_t + C_t.  Range: P in [e^-34, e^25] worst case — safe.
__global__ __launch_bounds__(768, 3)
void crf_fwd(const float* __restrict__ emis,      // [B,T,C]
             const float* __restrict__ trans,     // [B,C,C]
             const int* __restrict__ seq_lens,    // [B]
             float* __restrict__ out_alpha,       // [B,T,C]
             float* __restrict__ out_logz)        // [B]
{
  const int b = blockIdx.x;
  const int tid = threadIdx.x;
  const int lane = tid & 63;
  const int wv = tid >> 6;        // 0..7 MFMA, 8..11 helper
  const int quad = lane >> 4;
  const int nl = lane & 15;
  const int k0q = quad * 8;
  const int col0 = (wv & 7) * 32 + nl;
  const int col1 = col0 + 16;
  const int j = tid - 512;        // helper column (negative for MFMA waves)

  __shared__ unsigned short __align__(16) s_pbf[2][CC];  // P (bf16), dbuf
  __shared__ float s_E[2][CC];                           // staged exp(e_t)
  __shared__ float __align__(16) s_last[CC];             // alpha at L-1

  const float* eb = emis + (size_t)b * TT * CC;
  float* ab = out_alpha + (size_t)b * TT * CC;
  const int L = seq_lens[b];

  // ---- B fragments (declared for all; initialized/used only by wv<8) ----
#define DECLB(q) v8s B0_##q, B1_##q;
  REP8(DECLB)

  float C = 0.f, LA = 0.f, LB = 0.f;   // helper state

  if (wv < 8) {
    const float* tb = trans + (size_t)b * CC * CC;
    const int n0 = col0;
#define INITB(q) { \
    const float* pp = tb + (size_t)(q * 32 + k0q) * CC + n0; \
    B0_##q = (v8s){ f2bf(__expf(pp[0*CC])), f2bf(__expf(pp[1*CC])), \
                    f2bf(__expf(pp[2*CC])), f2bf(__expf(pp[3*CC])), \
                    f2bf(__expf(pp[4*CC])), f2bf(__expf(pp[5*CC])), \
                    f2bf(__expf(pp[6*CC])), f2bf(__expf(pp[7*CC])) }; \
    const float* qq = pp + 16; \
    B1_##q = (v8s){ f2bf(__expf(qq[0*CC])), f2bf(__expf(qq[1*CC])), \
                    f2bf(__expf(qq[2*CC])), f2bf(__expf(qq[3*CC])), \
                    f2bf(__expf(qq[4*CC])), f2bf(__expf(qq[5*CC])), \
                    f2bf(__expf(qq[6*CC])), f2bf(__expf(qq[7*CC])) }; }
    REP8(INITB)
  } else {
    // ---- helper prologue: t = 0 state ----
    float e0j = eb[j];
    float a00 = eb[0];
    ab[j] = e0j;                                   // alpha_0 exact
    C = a00;                                       // C_0
    s_pbf[0][j] = (unsigned short)f2bf(__expf(e0j - a00));
    // note: j==0 gives f2bf(exp(0)) = 1.0 exactly -> sigma_1 = 1.0
    if (L == 1) s_last[j] = e0j;
    s_E[1][j] = __expf(eb[CC + j]);                // E_1 for step t=1
    LB = eb[2 * CC + j];                           // e[2] in flight
  }
  const v4f z4 = {0.f, 0.f, 0.f, 0.f};
  __syncthreads();

  // ---- step macros ----
#define MSTEP(T, RB, WB) { \
    const unsigned short* pbR = s_pbf[RB]; \
    /* all 8 A-chunk reads issued back-to-back, before any lgkm use */ \
    v8s a0 = *(const v8s*)(const void*)(pbR + 0 * 32 + k0q); \
    v8s a1 = *(const v8s*)(const void*)(pbR + 1 * 32 + k0q); \
    v8s a2 = *(const v8s*)(const void*)(pbR + 2 * 32 + k0q); \
    v8s a3 = *(const v8s*)(const void*)(pbR + 3 * 32 + k0q); \
    v8s a4 = *(const v8s*)(const void*)(pbR + 4 * 32 + k0q); \
    v8s a5 = *(const v8s*)(const void*)(pbR + 5 * 32 + k0q); \
    v8s a6 = *(const v8s*)(const void*)(pbR + 6 * 32 + k0q); \
    v8s a7 = *(const v8s*)(const void*)(pbR + 7 * 32 + k0q); \
    float E0 = s_E[WB][col0]; \
    float E1 = s_E[WB][col1]; \
    unsigned pf = (unsigned)__builtin_amdgcn_readfirstlane(((v4i)a0)[0]); \
    float sig = __uint_as_float(pf << 16);                /* P_{t-1}[0] */ \
    float inv = __builtin_amdgcn_rcpf(sig); \
    v4f c0a, c0b, c1a, c1b; \
    __builtin_amdgcn_s_setprio(1);        /* T5: narrow window (R7) */ \
    c0a = __builtin_amdgcn_mfma_f32_16x16x32_bf16(a0, B0_0, z4, 0, 0, 0); \
    c1a = __builtin_amdgcn_mfma_f32_16x16x32_bf16(a0, B1_0, z4, 0, 0, 0); \
    c0b = __builtin_amdgcn_mfma_f32_16x16x32_bf16(a4, B0_4, z4, 0, 0, 0); \
    c1b = __builtin_amdgcn_mfma_f32_16x16x32_bf16(a4, B1_4, z4, 0, 0, 0); \
    c0a = __builtin_amdgcn_mfma_f32_16x16x32_bf16(a1, B0_1, c0a, 0, 0, 0); \
    c1a = __builtin_amdgcn_mfma_f32_16x16x32_bf16(a1, B1_1, c1a, 0, 0, 0); \
    c0b = __builtin_amdgcn_mfma_f32_16x16x32_bf16(a5, B0_5, c0b, 0, 0, 0); \
    c1b = __builtin_amdgcn_mfma_f32_16x16x32_bf16(a5, B1_5, c1b, 0, 0, 0); \
    c0a = __builtin_amdgcn_mfma_f32_16x16x32_bf16(a2, B0_2, c0a, 0, 0, 0); \
    c1a = __builtin_amdgcn_mfma_f32_16x16x32_bf16(a2, B1_2, c1a, 0, 0, 0); \
    c0b = __builtin_amdgcn_mfma_f32_16x16x32_bf16(a6, B0_6, c0b, 0, 0, 0); \
    c1b = __builtin_amdgcn_mfma_f32_16x16x32_bf16(a6, B1_6, c1b, 0, 0, 0); \
    c0a = __builtin_amdgcn_mfma_f32_16x16x32_bf16(a3, B0_3, c0a, 0, 0, 0); \
    c1a = __builtin_amdgcn_mfma_f32_16x16x32_bf16(a3, B1_3, c1a, 0, 0, 0); \
    c0b = __builtin_amdgcn_mfma_f32_16x16x32_bf16(a7, B0_7, c0b, 0, 0, 0); \
    c1b = __builtin_amdgcn_mfma_f32_16x16x32_bf16(a7, B1_7, c1b, 0, 0, 0); \
    __builtin_amdgcn_s_setprio(0); \
    float Ei0 = E0 * inv;                 /* in the MFMA shadow */ \
    float Ei1 = E1 * inv; \
    float r0 = c0a[0] + c0b[0]; \
    float r1 = c1a[0] + c1b[0]; \
    float v0 = Ei0 * r0; \
    float v1 = Ei1 * r1; \
    if (quad < 2) \
      s_pbf[WB][col0 + (quad << 4)] = (unsigned short)f2bf(quad ? v1 : v0); \
  }

  // helper: at step T stage E_{T+1} into s_E[(T+1)&1] == s_E[RB]
#define HSTEP(T, RB, WB, LDREG, USEREG) { \
    int tp2 = (T) + 2; if (tp2 > TT - 1) tp2 = TT - 1; \
    LDREG = eb[(size_t)tp2 * CC + j]; \
    unsigned short sg = s_pbf[RB][0];                     /* sigma bf16 */ \
    float sig = __uint_as_float(((unsigned)sg) << 16); \
    float P = __uint_as_float(((unsigned)s_pbf[RB][j]) << 16); \
    float a_prev = __logf(P) + C; \
    if ((T) >= 2) ab[(size_t)((T) - 1) * CC + j] = a_prev; \
    if ((T) == L) s_last[j] = a_prev; \
    C += __logf(sig); \
    if ((T) < TT - 1) s_E[RB][j] = __expf(USEREG); \
  }

  // ---- main chain: unroll-2, one fast_barrier per step ----
  for (int t = 1; t + 1 < TT; t += 2) {
    if (wv < 8) { MSTEP(t, 0, 1) } else { HSTEP(t, 0, 1, LA, LB) }
    fast_barrier();
    if (wv < 8) { MSTEP(t + 1, 1, 0) } else { HSTEP(t + 1, 1, 0, LB, LA) }
    fast_barrier();
  }
  // tail step t = TT-1 (odd): RB=0, WB=1
  if (wv < 8) { MSTEP(TT - 1, 0, 1) } else { HSTEP(TT - 1, 0, 1, LA, LB) }
  fast_barrier();

  // ---- epilogue: alpha_{TT-1} by helpers, then log_Z ----
  if (wv >= 8) {
    float P = __uint_as_float(((unsigned)s_pbf[(TT - 1) & 1][j]) << 16);
    float a_last = __logf(P) + C;                  // C == C_{TT-1}
    ab[(size_t)(TT - 1) * CC + j] = a_last;
    if (L == TT) s_last[j] = a_last;
  }
  __syncthreads();

  if (tid < 64) {
    float4 v = ((const float4*)s_last)[lane];
    float m = fmaxf(fmaxf(v.x, v.y), fmaxf(v.z, v.w));
    #pragma unroll
    for (int off = 32; off >= 1; off >>= 1)
      m = fmaxf(m, __shfl_xor(m, off, 64));
    float s = __expf(v.x - m) + __expf(v.y - m) + __expf(v.z - m) + __expf(v.w - m);
    #pragma unroll
    for (int off = 32; off >= 1; off >>= 1)
      s += __shfl_xor(s, off, 64);
    if (lane == 0) out_logz[b] = m + __logf(s);
  }
}

extern "C" void kernel_launch(void* const* d_in, const int* in_sizes, int n_in,
                              void* d_out, int out_size, void* d_ws, size_t ws_size,
                              hipStream_t stream) {
  const float* emis = (const float*)d_in[0];
  const float* trans = (const float*)d_in[1];
  const int* seq_lens = (const int*)d_in[2];
  float* out_alpha = (float*)d_out;
  float* out_logz = out_alpha + (size_t)BB * TT * CC;
  hipLaunchKernelGGL(crf_fwd, dim3(BB), dim3(768), 0, stream,
                     emis, trans, seq_lens, out_alpha, out_logz);
}